// Round 18
// baseline (100.084 us; speedup 1.0000x reference)
//
#include <hip/hip_runtime.h>
#include <hip/hip_cooperative_groups.h>

namespace cg = cooperative_groups;

#define NPROP 8192
#define NBLK 8
#define NT 1024
typedef unsigned long long u64;

__device__ __forceinline__ int bucket_of(float s) {
    int b = (int)(s * 8192.0f);   // exact: *2^13 is an exponent shift
    return b < 0 ? 0 : (b > NPROP - 1 ? NPROP - 1 : b);
}

__device__ __forceinline__ bool iou_gt_thr(float4 a, float4 b) {
    float areaA = (a.z - a.x) * (a.w - a.y);
    float areaB = (b.z - b.x) * (b.w - b.y);
    float lx = fmaxf(a.x, b.x), ly = fmaxf(a.y, b.y);
    float rx = fminf(a.z, b.z), ry = fminf(a.w, b.w);
    float w = fmaxf(rx - lx, 0.0f), h = fmaxf(ry - ly, 0.0f);
    float inter = w * h;
    float uni = areaA + areaB - inter;
    float iou = inter / fmaxf(uni, 1e-6f);
    return iou > 0.3f;
}

// ================= cooperative mega-kernel =================
__global__ __launch_bounds__(NT)
void k_mega(const float* __restrict__ boxes, const float* __restrict__ scores,
            const float* __restrict__ img,
            int* hist, unsigned* prefP, int* tmp_idx, unsigned char* vbyte,
            float* srt_s, float4* srt_box, float4* cbox, int* crank,
            int* meta, u64* remG, u64* mask, float* out) {
    cg::grid_group grid = cg::this_grid();
    __shared__ int wsum[16], wexcl[16];
    __shared__ u64 rem[NPROP / 64];
    __shared__ u64 diagb[2][64];
    __shared__ u64 nextw[64];
    __shared__ u64 pullw[2];
    __shared__ int klidx[NPROP];
    __shared__ int Ksh;

    const int tid = threadIdx.x, lane = tid & 63, wave = tid >> 6;
    const int GT = blockIdx.x * NT + tid;   // 0..8191 == one proposal / position

    // ---- P0: validity + zero hist ----
    {
        float4 bx = reinterpret_cast<const float4*>(boxes)[GT];
        float s = scores[GT];
        float ix1 = img[0], iy1 = img[1], ix2 = img[2], iy2 = img[3];
        float img_area = (ix2 - ix1) * (iy2 - iy1);
        float w = bx.z - bx.x, h = bx.w - bx.y;
        float ratio = w / (h + 1e-12f);
        bool vs = (ratio > 0.25f) && (ratio < 4.0f);
        float lx = fmaxf(ix1, bx.x), ly = fmaxf(iy1, bx.y);
        float rx = fminf(ix2, bx.z), ry = fminf(iy2, bx.w);
        float iw = fmaxf(rx - lx, 0.0f), ih = fmaxf(ry - ly, 0.0f);
        float iof = (iw * ih) / fmaxf(img_area, 1e-6f);
        vbyte[GT] = (vs && (iof > 0.01f) && (s > 0.85f)) ? 1 : 0;
        hist[GT] = 0;
    }
    grid.sync();

    // ---- P1: packed histogram (all | valid<<16) ----
    {
        float s = scores[GT];
        int vf = (int)vbyte[GT];
        atomicAdd(&hist[bucket_of(s)], 1 + (vf << 16));
    }
    grid.sync();

    // ---- P2: scan over 8192 buckets (block 0) + allocator + meta ----
    if (blockIdx.x == 0) {
        int h[8]; int tot = 0;
        #pragma unroll
        for (int u = 0; u < 8; u++) { h[u] = hist[tid * 8 + u]; tot += h[u]; }
        int incl = tot;
        #pragma unroll
        for (int off = 1; off < 64; off <<= 1) {
            int n = __shfl_up(incl, off, 64);
            if (lane >= off) incl += n;
        }
        if (lane == 63) wsum[wave] = incl;
        __syncthreads();
        if (tid == 0) {
            int acc = 0;
            #pragma unroll
            for (int w = 0; w < 16; w++) { int t = wsum[w]; wexcl[w] = acc; acc += t; }
            int Vraw = acc >> 16;
            int V = Vraw == 0 ? 1 : Vraw;
            meta[0] = V;
            meta[1] = (V + 63) >> 6;
            meta[2] = Vraw;
        }
        __syncthreads();
        int run = wexcl[wave] + (incl - tot);   // packed prefix
        int runA = run & 0xffff;                // all-count prefix (allocator)
        #pragma unroll
        for (int u = 0; u < 8; u++) { prefP[tid * 8 + u] = (unsigned)run; run += h[u]; }
        #pragma unroll
        for (int u = 0; u < 8; u++) { hist[tid * 8 + u] = runA; runA += h[u] & 0xffff; }
    }
    grid.sync();

    // ---- P3: scatter into bucket-grouped order (validity-tagged) ----
    {
        float s = scores[GT];
        int vf = (int)vbyte[GT];
        int slot = atomicAdd(&hist[bucket_of(s)], 1);
        tmp_idx[slot] = GT | (vf << 31);
    }
    grid.sync();

    // ---- P4: exact stable rank + compact position ----
    {
        int ip = tmp_idx[GT];
        int i = ip & 0xffff;
        bool vf = ip < 0;
        float s = scores[i];
        u64 key = ((u64)__float_as_uint(s) << 32) | (u64)(unsigned)(NPROP - 1 - i);
        int b = bucket_of(s);
        unsigned pb = prefP[b];
        int lo = (int)(pb & 0xffffu), vlo = (int)(pb >> 16);
        int hi = (b < NPROP - 1) ? (int)(prefP[b + 1] & 0xffffu) : NPROP;
        int cnt2 = 0, vcnt = 0;
        for (int q = lo; q < hi; q++) {
            int jp = tmp_idx[q];
            int j = jp & 0xffff;
            int vfj = (int)((unsigned)jp >> 31);
            u64 kj = ((u64)__float_as_uint(scores[j]) << 32) | (u64)(unsigned)(NPROP - 1 - j);
            int less = (kj < key) ? 1 : 0;
            cnt2 += less; vcnt += less & vfj;
        }
        int rank = NPROP - 1 - (lo + cnt2);     // descending, stable
        float4 bx = reinterpret_cast<const float4*>(boxes)[i];
        srt_box[rank] = bx;
        srt_s[rank] = s;
        int Vraw = meta[2];
        if (vf) {
            int cpos = Vraw - 1 - (vlo + vcnt);
            crank[rank] = cpos;
            cbox[cpos] = bx;
        } else {
            crank[rank] = -1;
        }
        if (Vraw == 0 && rank == 0) { crank[0] = 0; cbox[0] = bx; }
    }
    grid.sync();

    // ---- P5: suppression mask, column-major mask[w*VP + r] ----
    {
        const int V = meta[0], W = meta[1];
        const int VP = W << 6;
        int gw = blockIdx.x * 16 + wave;        // 128 wave slots
        for (int r = gw; r < V; r += NBLK * 16) {
            float4 br = cbox[r];
            for (int w = (r >> 6); w < W; w++) {
                int col = w * 64 + lane;
                bool ok = (col < V) && (col > r) && iou_gt_thr(br, cbox[col]);
                u64 bal = __ballot(ok);
                if (lane == 0) mask[(u64)w * VP + r] = bal;
            }
        }
    }
    grid.sync();

    // ---- P6: pipelined pull-resolve (block 0) ----
    if (blockIdx.x == 0) {
        const int V = meta[0], W = meta[1];
        const int VP = W << 6;
        for (int w = tid; w < NPROP / 64; w += NT) {
            int b0 = w * 64; u64 m;
            if (b0 >= V) m = ~0ull;
            else if (b0 + 64 <= V) m = 0ull;
            else m = (~0ull) << (V - b0);
            rem[w] = m;
        }
        if (tid == 0) { Ksh = 0; pullw[0] = 0; pullw[1] = 0; }
        if (wave == 15) diagb[0][lane] = (lane < V) ? mask[lane] : 0ull;
        __syncthreads();

        for (int b = 0; b < W; b++) {
            const int rb0 = b << 6;
            const int nb = b + 1;
            const int K = Ksh;
            u64 keptb = 0;
            if (wave == 0) {
                u64 d = diagb[b & 1][lane];
                int dlo = (int)(unsigned)(d & 0xffffffffull);
                int dhi = (int)(unsigned)(d >> 32);
                u64 r0 = rem[b] | pullw[b & 1];
                unsigned rl_ = (unsigned)__builtin_amdgcn_readfirstlane((int)(unsigned)(r0 & 0xffffffffull));
                unsigned rh_ = (unsigned)__builtin_amdgcn_readfirstlane((int)(unsigned)(r0 >> 32));
                u64 r = ((u64)rh_ << 32) | (u64)rl_;
                u64 avail = ~r;
                while (avail) {
                    int i = (int)__builtin_ctzll(avail);
                    unsigned xl = (unsigned)__builtin_amdgcn_readlane(dlo, i);
                    unsigned xh = (unsigned)__builtin_amdgcn_readlane(dhi, i);
                    u64 di = ((u64)xh << 32) | (u64)xl;
                    r |= di;
                    u64 x = avail & ~di;
                    avail = x & (x - 1);
                }
                keptb = ~r;
                if (lane == 0) rem[b] = r;
            } else if (wave <= 13) {
                if (nb < W) {
                    u64 myor = 0;
                    for (int t = (wave - 1) * 64 + lane; t < K; t += 13 * 64)
                        myor |= mask[(u64)nb * VP + klidx[t]];
                    #pragma unroll
                    for (int off = 1; off < 64; off <<= 1)
                        myor |= __shfl_xor(myor, off, 64);
                    if (lane == 0 && myor)
                        atomicOr((unsigned long long*)&pullw[nb & 1], myor);
                }
            } else if (wave == 14) {
                if (nb < W) {
                    int r_ = rb0 + lane;
                    nextw[lane] = (r_ < V) ? mask[(u64)nb * VP + r_] : 0ull;
                }
            } else {
                if (nb < W) {
                    int r_ = (nb << 6) + lane;
                    diagb[nb & 1][lane] = (r_ < V) ? mask[(u64)nb * VP + r_] : 0ull;
                }
            }
            __syncthreads();
            if (wave == 0) {
                if (nb < W) {
                    u64 t = ((keptb >> lane) & 1ull) ? nextw[lane] : 0ull;
                    #pragma unroll
                    for (int off = 1; off < 64; off <<= 1)
                        t |= __shfl_xor(t, off, 64);
                    if (lane == 0 && t)
                        atomicOr((unsigned long long*)&pullw[nb & 1], t);
                }
                if ((keptb >> lane) & 1ull) {
                    int pos = (int)__popcll(keptb & ((1ull << lane) - 1ull));
                    klidx[K + pos] = rb0 + lane;
                }
                if (lane == 0) Ksh = K + (int)__popcll(keptb);
            } else if (tid == 64) {
                pullw[b & 1] = 0;
            }
            __syncthreads();
        }
        for (int w = tid; w < NPROP / 64; w += NT) remG[w] = rem[w];
    }
    grid.sync();

    // ---- P7: output [N,5]*keep + keep mask (first 2048 threads, 4 pos each) ----
    if (GT < 2048) {
        float ob[20]; float om[4];
        #pragma unroll
        for (int u = 0; u < 4; u++) {
            int p = GT * 4 + u;
            float4 b = srt_box[p];
            float s = srt_s[p];
            int k = crank[p];
            bool keep = (k >= 0) && !((remG[k >> 6] >> (k & 63)) & 1ull);
            float m = keep ? 1.0f : 0.0f;
            ob[u * 5 + 0] = b.x * m;
            ob[u * 5 + 1] = b.y * m;
            ob[u * 5 + 2] = b.z * m;
            ob[u * 5 + 3] = b.w * m;
            ob[u * 5 + 4] = s * m;
            om[u] = m;
        }
        float4* o4 = reinterpret_cast<float4*>(out) + GT * 5;
        #pragma unroll
        for (int q = 0; q < 5; q++)
            o4[q] = make_float4(ob[q * 4 + 0], ob[q * 4 + 1], ob[q * 4 + 2], ob[q * 4 + 3]);
        reinterpret_cast<float4*>(out + NPROP * 5)[GT] =
            make_float4(om[0], om[1], om[2], om[3]);
    }
}

// ================= fallback pipeline (proven R16) =================
__global__ __launch_bounds__(256)
void k_valid(const float* __restrict__ boxes, const float* __restrict__ scores,
             const float* __restrict__ img, unsigned char* __restrict__ vbyte) {
    int i = blockIdx.x * 256 + threadIdx.x;
    float4 bx = reinterpret_cast<const float4*>(boxes)[i];
    float s = scores[i];
    float ix1 = img[0], iy1 = img[1], ix2 = img[2], iy2 = img[3];
    float img_area = (ix2 - ix1) * (iy2 - iy1);
    float w = bx.z - bx.x, h = bx.w - bx.y;
    float ratio = w / (h + 1e-12f);
    bool vs = (ratio > 0.25f) && (ratio < 4.0f);
    float lx = fmaxf(ix1, bx.x), ly = fmaxf(iy1, bx.y);
    float rx = fminf(ix2, bx.z), ry = fminf(iy2, bx.w);
    float iw = fmaxf(rx - lx, 0.0f), ih = fmaxf(ry - ly, 0.0f);
    float iof = (iw * ih) / fmaxf(img_area, 1e-6f);
    vbyte[i] = (vs && (iof > 0.01f) && (s > 0.85f)) ? 1 : 0;
}

__global__ __launch_bounds__(NT)
void k_sort1(const float* __restrict__ scores, const unsigned char* __restrict__ vbyte,
             unsigned* __restrict__ prefP, int* __restrict__ tmp_idx,
             int* __restrict__ meta) {
    __shared__ int hist[NPROP];
    __shared__ int wsum[16], wexcl[16];
    const int tid = threadIdx.x, lane = tid & 63, wave = tid >> 6;
    #pragma unroll
    for (int u = 0; u < 8; u++) hist[tid * 8 + u] = 0;
    __syncthreads();
    const float4* s4 = reinterpret_cast<const float4*>(scores);
    float4 sa = s4[tid * 2], sb = s4[tid * 2 + 1];
    float ss[8] = {sa.x, sa.y, sa.z, sa.w, sb.x, sb.y, sb.z, sb.w};
    u64 vb8 = reinterpret_cast<const u64*>(vbyte)[tid];
    int bk[8], vf[8];
    #pragma unroll
    for (int u = 0; u < 8; u++) {
        bk[u] = bucket_of(ss[u]);
        vf[u] = (int)((vb8 >> (8 * u)) & 1ull);
        atomicAdd(&hist[bk[u]], 1 + (vf[u] << 16));
    }
    __syncthreads();
    int h[8]; int tot = 0;
    #pragma unroll
    for (int u = 0; u < 8; u++) { h[u] = hist[tid * 8 + u]; tot += h[u]; }
    int incl = tot;
    #pragma unroll
    for (int off = 1; off < 64; off <<= 1) {
        int n = __shfl_up(incl, off, 64);
        if (lane >= off) incl += n;
    }
    if (lane == 63) wsum[wave] = incl;
    __syncthreads();
    if (tid == 0) {
        int acc = 0;
        #pragma unroll
        for (int w = 0; w < 16; w++) { int t = wsum[w]; wexcl[w] = acc; acc += t; }
        int Vraw = acc >> 16;
        int V = Vraw == 0 ? 1 : Vraw;
        meta[0] = V;
        meta[1] = (V + 63) >> 6;
        meta[2] = Vraw;
    }
    __syncthreads();
    int run = wexcl[wave] + (incl - tot);
    int runA = run & 0xffff;
    #pragma unroll
    for (int u = 0; u < 8; u++) { prefP[tid * 8 + u] = (unsigned)run; run += h[u]; }
    __syncthreads();
    #pragma unroll
    for (int u = 0; u < 8; u++) { hist[tid * 8 + u] = runA; runA += h[u] & 0xffff; }
    __syncthreads();
    #pragma unroll
    for (int u = 0; u < 8; u++) {
        int slot = atomicAdd(&hist[bk[u]], 1);
        tmp_idx[slot] = (tid * 8 + u) | (vf[u] << 31);
    }
}

__global__ void k_rank(const float* __restrict__ scores, const float* __restrict__ boxes,
                       const int* __restrict__ tmp_idx, const unsigned* __restrict__ prefP,
                       const int* __restrict__ meta,
                       float4* __restrict__ srt_box, float* __restrict__ srt_s,
                       int* __restrict__ crank, float4* __restrict__ cbox) {
    int p = blockIdx.x * blockDim.x + threadIdx.x;
    int ip = tmp_idx[p];
    int i = ip & 0xffff;
    bool vf = ip < 0;
    float s = scores[i];
    u64 key = ((u64)__float_as_uint(s) << 32) | (u64)(unsigned)(NPROP - 1 - i);
    int b = bucket_of(s);
    unsigned pb = prefP[b];
    int lo = (int)(pb & 0xffffu), vlo = (int)(pb >> 16);
    int hi = (b < NPROP - 1) ? (int)(prefP[b + 1] & 0xffffu) : NPROP;
    int cnt = 0, vcnt = 0;
    for (int q = lo; q < hi; q++) {
        int jp = tmp_idx[q];
        int j = jp & 0xffff;
        int vfj = (int)((unsigned)jp >> 31);
        u64 kj = ((u64)__float_as_uint(scores[j]) << 32) | (u64)(unsigned)(NPROP - 1 - j);
        int less = (kj < key) ? 1 : 0;
        cnt += less; vcnt += less & vfj;
    }
    int rank = NPROP - 1 - (lo + cnt);
    float4 bx = reinterpret_cast<const float4*>(boxes)[i];
    srt_box[rank] = bx;
    srt_s[rank] = s;
    int Vraw = meta[2];
    if (vf) {
        int cpos = Vraw - 1 - (vlo + vcnt);
        crank[rank] = cpos;
        cbox[cpos] = bx;
    } else {
        crank[rank] = -1;
    }
    if (Vraw == 0 && rank == 0) { crank[0] = 0; cbox[0] = bx; }
}

__global__ __launch_bounds__(256)
void k_mask(const float4* __restrict__ cbox, const int* __restrict__ meta,
            u64* __restrict__ mask) {
    const int V = meta[0], W = meta[1];
    const int VP = W << 6;
    const int lane = threadIdx.x & 63;
    int gw = blockIdx.x * 4 + (threadIdx.x >> 6);
    for (int r = gw; r < V; r += 1024) {
        float4 br = cbox[r];
        for (int w = (r >> 6); w < W; w++) {
            int col = w * 64 + lane;
            bool ok = (col < V) && (col > r) && iou_gt_thr(br, cbox[col]);
            u64 bal = __ballot(ok);
            if (lane == 0) mask[(u64)w * VP + r] = bal;
        }
    }
}

__global__ __launch_bounds__(NT)
void k_resolve(const u64* __restrict__ mask, const int* __restrict__ meta,
               u64* __restrict__ remG) {
    __shared__ u64 rem[NPROP / 64];
    __shared__ u64 diagb[2][64];
    __shared__ u64 nextw[64];
    __shared__ u64 pullw[2];
    __shared__ int klidx[NPROP];
    __shared__ int Ksh;
    const int V = meta[0], W = meta[1];
    const int VP = W << 6;
    const int tid = threadIdx.x, lane = tid & 63, wave = tid >> 6;

    for (int w = tid; w < NPROP / 64; w += NT) {
        int b0 = w * 64; u64 m;
        if (b0 >= V) m = ~0ull;
        else if (b0 + 64 <= V) m = 0ull;
        else m = (~0ull) << (V - b0);
        rem[w] = m;
    }
    if (tid == 0) { Ksh = 0; pullw[0] = 0; pullw[1] = 0; }
    if (wave == 15) diagb[0][lane] = (lane < V) ? mask[lane] : 0ull;
    __syncthreads();

    for (int b = 0; b < W; b++) {
        const int rb0 = b << 6;
        const int nb = b + 1;
        const int K = Ksh;
        u64 keptb = 0;
        if (wave == 0) {
            u64 d = diagb[b & 1][lane];
            int dlo = (int)(unsigned)(d & 0xffffffffull);
            int dhi = (int)(unsigned)(d >> 32);
            u64 r0 = rem[b] | pullw[b & 1];
            unsigned rl_ = (unsigned)__builtin_amdgcn_readfirstlane((int)(unsigned)(r0 & 0xffffffffull));
            unsigned rh_ = (unsigned)__builtin_amdgcn_readfirstlane((int)(unsigned)(r0 >> 32));
            u64 r = ((u64)rh_ << 32) | (u64)rl_;
            u64 avail = ~r;
            while (avail) {
                int i = (int)__builtin_ctzll(avail);
                unsigned xl = (unsigned)__builtin_amdgcn_readlane(dlo, i);
                unsigned xh = (unsigned)__builtin_amdgcn_readlane(dhi, i);
                u64 di = ((u64)xh << 32) | (u64)xl;
                r |= di;
                u64 x = avail & ~di;
                avail = x & (x - 1);
            }
            keptb = ~r;
            if (lane == 0) rem[b] = r;
        } else if (wave <= 13) {
            if (nb < W) {
                u64 myor = 0;
                for (int t = (wave - 1) * 64 + lane; t < K; t += 13 * 64)
                    myor |= mask[(u64)nb * VP + klidx[t]];
                #pragma unroll
                for (int off = 1; off < 64; off <<= 1)
                    myor |= __shfl_xor(myor, off, 64);
                if (lane == 0 && myor)
                    atomicOr((unsigned long long*)&pullw[nb & 1], myor);
            }
        } else if (wave == 14) {
            if (nb < W) {
                int r_ = rb0 + lane;
                nextw[lane] = (r_ < V) ? mask[(u64)nb * VP + r_] : 0ull;
            }
        } else {
            if (nb < W) {
                int r_ = (nb << 6) + lane;
                diagb[nb & 1][lane] = (r_ < V) ? mask[(u64)nb * VP + r_] : 0ull;
            }
        }
        __syncthreads();
        if (wave == 0) {
            if (nb < W) {
                u64 t = ((keptb >> lane) & 1ull) ? nextw[lane] : 0ull;
                #pragma unroll
                for (int off = 1; off < 64; off <<= 1)
                    t |= __shfl_xor(t, off, 64);
                if (lane == 0 && t)
                    atomicOr((unsigned long long*)&pullw[nb & 1], t);
            }
            if ((keptb >> lane) & 1ull) {
                int pos = (int)__popcll(keptb & ((1ull << lane) - 1ull));
                klidx[K + pos] = rb0 + lane;
            }
            if (lane == 0) Ksh = K + (int)__popcll(keptb);
        } else if (tid == 64) {
            pullw[b & 1] = 0;
        }
        __syncthreads();
    }

    for (int w = tid; w < NPROP / 64; w += NT) remG[w] = rem[w];
}

__global__ __launch_bounds__(256)
void k_out(const float4* __restrict__ srt_box, const float* __restrict__ srt_s,
           const int* __restrict__ crank, const u64* __restrict__ remG,
           float* __restrict__ out) {
    int tid = blockIdx.x * 256 + threadIdx.x;
    float ob[20]; float om[4];
    #pragma unroll
    for (int u = 0; u < 4; u++) {
        int p = tid * 4 + u;
        float4 b = srt_box[p];
        float s = srt_s[p];
        int k = crank[p];
        bool keep = (k >= 0) && !((remG[k >> 6] >> (k & 63)) & 1ull);
        float m = keep ? 1.0f : 0.0f;
        ob[u * 5 + 0] = b.x * m;
        ob[u * 5 + 1] = b.y * m;
        ob[u * 5 + 2] = b.z * m;
        ob[u * 5 + 3] = b.w * m;
        ob[u * 5 + 4] = s * m;
        om[u] = m;
    }
    float4* o4 = reinterpret_cast<float4*>(out) + tid * 5;
    #pragma unroll
    for (int q = 0; q < 5; q++)
        o4[q] = make_float4(ob[q * 4 + 0], ob[q * 4 + 1], ob[q * 4 + 2], ob[q * 4 + 3]);
    reinterpret_cast<float4*>(out + NPROP * 5)[tid] =
        make_float4(om[0], om[1], om[2], om[3]);
}

extern "C" void kernel_launch(void* const* d_in, const int* in_sizes, int n_in,
                              void* d_out, int out_size, void* d_ws, size_t ws_size,
                              hipStream_t stream) {
    const float* boxes  = (const float*)d_in[0];
    const float* scores = (const float*)d_in[1];
    const float* img    = (const float*)d_in[2];
    char* ws = (char*)d_ws;
    int*    hist     = (int*)(ws + 0);                   // 32 KiB (mega only)
    unsigned* prefP  = (unsigned*)(ws + 32768);          // 32 KiB
    int*    tmp_idx  = (int*)(ws + 65536);               // 32 KiB
    unsigned char* vbyte = (unsigned char*)(ws + 98304); // 8 KiB
    float*  srt_s    = (float*)(ws + 106496);            // 32 KiB
    float4* srt_box  = (float4*)(ws + 139264);           // 128 KiB
    float4* cbox     = (float4*)(ws + 270336);           // 128 KiB
    int*    crank    = (int*)(ws + 401408);              // 32 KiB
    int*    meta     = (int*)(ws + 434176);              // 1 KiB
    u64*    remG     = (u64*)(ws + 435200);              // 1 KiB
    u64*    mask     = (u64*)(ws + 436224);              // W*VP*8 B (~200 KiB realistic)
    float* out = (float*)d_out;

    void* args[] = { (void*)&boxes, (void*)&scores, (void*)&img,
                     (void*)&hist, (void*)&prefP, (void*)&tmp_idx, (void*)&vbyte,
                     (void*)&srt_s, (void*)&srt_box, (void*)&cbox, (void*)&crank,
                     (void*)&meta, (void*)&remG, (void*)&mask, (void*)&out };
    hipError_t err = hipLaunchCooperativeKernel((void*)k_mega, dim3(NBLK), dim3(NT),
                                                args, 0, stream);
    if (err != hipSuccess) {
        // fallback: proven 6-kernel pipeline (identical math & output)
        k_valid<<<32, 256, 0, stream>>>(boxes, scores, img, vbyte);
        k_sort1<<<1, NT, 0, stream>>>(scores, vbyte, prefP, tmp_idx, meta);
        k_rank<<<32, 256, 0, stream>>>(scores, boxes, tmp_idx, prefP, meta,
                                       srt_box, srt_s, crank, cbox);
        k_mask<<<256, 256, 0, stream>>>(cbox, meta, mask);
        k_resolve<<<1, NT, 0, stream>>>(mask, meta, remG);
        k_out<<<8, 256, 0, stream>>>(srt_box, srt_s, crank, remG, out);
    }
}

// Round 20
// 44.385 us; speedup vs baseline: 2.2549x; 2.2549x over previous
//
#include <hip/hip_runtime.h>

#define NPROP 8192
#define NT 1024
typedef unsigned long long u64;

__device__ __forceinline__ int bucket_of(float s) {
    int b = (int)(s * 8192.0f);   // exact: *2^13 is an exponent shift
    return b < 0 ? 0 : (b > NPROP - 1 ? NPROP - 1 : b);
}

__device__ __forceinline__ bool iou_gt_thr(float4 a, float4 b) {
    float areaA = (a.z - a.x) * (a.w - a.y);
    float areaB = (b.z - b.x) * (b.w - b.y);
    float lx = fmaxf(a.x, b.x), ly = fmaxf(a.y, b.y);
    float rx = fminf(a.z, b.z), ry = fminf(a.w, b.w);
    float w = fmaxf(rx - lx, 0.0f), h = fmaxf(ry - ly, 0.0f);
    float inter = w * h;
    float uni = areaA + areaB - inter;
    float iou = inter / fmaxf(uni, 1e-6f);
    return iou > 0.3f;
}

// K1: validity + packed LDS histogram (all | valid<<16) + scan + tagged scatter
__global__ __launch_bounds__(NT)
void k_sort1(const float* __restrict__ boxes, const float* __restrict__ scores,
             const float* __restrict__ img,
             unsigned* __restrict__ prefP, int* __restrict__ tmp_idx,
             int* __restrict__ meta) {
    __shared__ int hist[NPROP];   // 32 KiB: packed counts -> allocator
    __shared__ int wsum[16], wexcl[16];
    const int tid = threadIdx.x, lane = tid & 63, wave = tid >> 6;
    #pragma unroll
    for (int u = 0; u < 8; u++) hist[tid * 8 + u] = 0;
    __syncthreads();
    float ix1 = img[0], iy1 = img[1], ix2 = img[2], iy2 = img[3];
    float img_area = (ix2 - ix1) * (iy2 - iy1);
    float ss[8]; int pp[8], bk[8], vf[8];
    #pragma unroll
    for (int u = 0; u < 8; u++) {
        int p = u * NT + tid;                 // coalesced per-u
        pp[u] = p;
        float s = scores[p];
        float4 bx = reinterpret_cast<const float4*>(boxes)[p];
        float w = bx.z - bx.x, h = bx.w - bx.y;
        float ratio = w / (h + 1e-12f);
        bool vs = (ratio > 0.25f) && (ratio < 4.0f);
        float lx = fmaxf(ix1, bx.x), ly = fmaxf(iy1, bx.y);
        float rx = fminf(ix2, bx.z), ry = fminf(iy2, bx.w);
        float iw = fmaxf(rx - lx, 0.0f), ih = fmaxf(ry - ly, 0.0f);
        float iof = (iw * ih) / fmaxf(img_area, 1e-6f);
        ss[u] = s;
        bk[u] = bucket_of(s);
        vf[u] = (vs && (iof > 0.01f) && (s > 0.85f)) ? 1 : 0;
        atomicAdd(&hist[bk[u]], 1 + (vf[u] << 16));
    }
    __syncthreads();
    int h[8]; int tot = 0;
    #pragma unroll
    for (int u = 0; u < 8; u++) { h[u] = hist[tid * 8 + u]; tot += h[u]; }
    int incl = tot;
    #pragma unroll
    for (int off = 1; off < 64; off <<= 1) {
        int n = __shfl_up(incl, off, 64);
        if (lane >= off) incl += n;
    }
    if (lane == 63) wsum[wave] = incl;
    __syncthreads();
    if (tid == 0) {
        int acc = 0;
        #pragma unroll
        for (int w = 0; w < 16; w++) { int t = wsum[w]; wexcl[w] = acc; acc += t; }
        int Vraw = acc >> 16;                 // total valid
        int V = Vraw == 0 ? 1 : Vraw;
        meta[0] = V;
        meta[1] = (V + 63) >> 6;
        meta[2] = Vraw;
    }
    __syncthreads();
    int run = wexcl[wave] + (incl - tot);     // packed prefix
    int runA = run & 0xffff;                  // all-count prefix (allocator)
    #pragma unroll
    for (int u = 0; u < 8; u++) { prefP[tid * 8 + u] = (unsigned)run; run += h[u]; }
    __syncthreads();   // all hist reads done before overwrite as allocator
    #pragma unroll
    for (int u = 0; u < 8; u++) { hist[tid * 8 + u] = runA; runA += h[u] & 0xffff; }
    __syncthreads();
    #pragma unroll
    for (int u = 0; u < 8; u++) {
        int slot = atomicAdd(&hist[bk[u]], 1);
        tmp_idx[slot] = pp[u] | (vf[u] << 31);   // validity-tagged index
    }
}

// K2: exact stable rank; ONLY valid proposals materialize (cbox/cscore/vrank)
__global__ void k_rank(const float* __restrict__ scores, const float* __restrict__ boxes,
                       const int* __restrict__ tmp_idx, const unsigned* __restrict__ prefP,
                       const int* __restrict__ meta,
                       float4* __restrict__ cbox, float* __restrict__ cscore,
                       int* __restrict__ vrank) {
    int p = blockIdx.x * blockDim.x + threadIdx.x;
    int ip = tmp_idx[p];
    int i = ip & 0xffff;
    bool vf = ip < 0;
    int Vraw = meta[2];
    float s = scores[i];
    u64 key = ((u64)__float_as_uint(s) << 32) | (u64)(unsigned)(NPROP - 1 - i);
    int b = bucket_of(s);
    unsigned pb = prefP[b];
    int lo = (int)(pb & 0xffffu), vlo = (int)(pb >> 16);
    int hi = (b < NPROP - 1) ? (int)(prefP[b + 1] & 0xffffu) : NPROP;
    int cnt = 0, vcnt = 0;
    for (int q = lo; q < hi; q++) {
        int jp = tmp_idx[q];
        int j = jp & 0xffff;
        int vfj = (int)((unsigned)jp >> 31);
        u64 kj = ((u64)__float_as_uint(scores[j]) << 32) | (u64)(unsigned)(NPROP - 1 - j);
        int less = (kj < key) ? 1 : 0;
        cnt += less; vcnt += less & vfj;
    }
    int rank = NPROP - 1 - (lo + cnt);        // descending, stable
    if (vf) {
        int cpos = Vraw - 1 - (vlo + vcnt);   // compact pos among valid (descending)
        float4 bx = reinterpret_cast<const float4*>(boxes)[i];
        cbox[cpos] = bx;
        cscore[cpos] = s;
        vrank[cpos] = rank;
    } else if (Vraw == 0 && rank == 0) {      // fallback: keep top-scoring only
        float4 bx = reinterpret_cast<const float4*>(boxes)[i];
        cbox[0] = bx;
        cscore[0] = s;
        vrank[0] = 0;
    }
}

// K3: zero the output buffer + build suppression mask (column-major mask[w*VP+r])
__global__ __launch_bounds__(256)
void k_mask(const float4* __restrict__ cbox, const int* __restrict__ meta,
            u64* __restrict__ mask, float* __restrict__ out) {
    int gid = blockIdx.x * 256 + threadIdx.x;
    if (gid < (NPROP * 6) / 4)                // 12288 float4 = 8192*(5+1) floats
        reinterpret_cast<float4*>(out)[gid] = make_float4(0.f, 0.f, 0.f, 0.f);
    const int V = meta[0], W = meta[1];
    const int VP = W << 6;
    const int lane = threadIdx.x & 63;
    int gw = blockIdx.x * 4 + (threadIdx.x >> 6);
    for (int r = gw; r < V; r += 1024) {
        float4 br = cbox[r];
        for (int w = (r >> 6); w < W; w++) {
            int col = w * 64 + lane;
            bool ok = (col < V) && (col > r) && iou_gt_thr(br, cbox[col]);
            u64 bal = __ballot(ok);
            if (lane == 0) mask[(u64)w * VP + r] = bal;
        }
    }
}

// K4: pipelined pull-resolve + direct kept-row scatter to out
__global__ __launch_bounds__(NT)
void k_resolve(const u64* __restrict__ mask, const int* __restrict__ meta,
               const float4* __restrict__ cbox, const float* __restrict__ cscore,
               const int* __restrict__ vrank, float* __restrict__ out) {
    __shared__ u64 rem[NPROP / 64];   // 1 KiB
    __shared__ u64 diagb[2][64];      // diag words, ping-pong
    __shared__ u64 nextw[64];         // rows of block b, col-word b+1
    __shared__ u64 pullw[2];
    __shared__ int klidx[NPROP];      // kept-row indices
    __shared__ int Ksh;
    const int V = meta[0], W = meta[1];
    const int VP = W << 6;
    const int tid = threadIdx.x, lane = tid & 63, wave = tid >> 6;

    for (int w = tid; w < NPROP / 64; w += NT) {
        int b0 = w * 64; u64 m;
        if (b0 >= V) m = ~0ull;
        else if (b0 + 64 <= V) m = 0ull;
        else m = (~0ull) << (V - b0);
        rem[w] = m;
    }
    if (tid == 0) { Ksh = 0; pullw[0] = 0; pullw[1] = 0; }
    if (wave == 15) diagb[0][lane] = (lane < V) ? mask[lane] : 0ull;
    __syncthreads();

    for (int b = 0; b < W; b++) {
        const int rb0 = b << 6;
        const int nb = b + 1;
        const int K = Ksh;            // kept through block b-1 (stable this phase)
        u64 keptb = 0;
        // ---- phase 1: chain(b) on wave 0 || prefetch for b+1 on waves 1..15 ----
        if (wave == 0) {
            u64 d = diagb[b & 1][lane];
            int dlo = (int)(unsigned)(d & 0xffffffffull);
            int dhi = (int)(unsigned)(d >> 32);
            u64 r0 = rem[b] | pullw[b & 1];
            unsigned rl_ = (unsigned)__builtin_amdgcn_readfirstlane((int)(unsigned)(r0 & 0xffffffffull));
            unsigned rh_ = (unsigned)__builtin_amdgcn_readfirstlane((int)(unsigned)(r0 >> 32));
            u64 r = ((u64)rh_ << 32) | (u64)rl_;
            u64 avail = ~r;           // candidates (pad bits pre-removed)
            while (avail) {
                int i = (int)__builtin_ctzll(avail);          // lowest candidate -> KEPT
                unsigned xl = (unsigned)__builtin_amdgcn_readlane(dlo, i);
                unsigned xh = (unsigned)__builtin_amdgcn_readlane(dhi, i);
                u64 di = ((u64)xh << 32) | (u64)xl;
                r |= di;
                u64 x = avail & ~di;
                avail = x & (x - 1);
            }
            keptb = ~r;
            if (lane == 0) rem[b] = r;
        } else if (wave <= 13) {
            if (nb < W) {             // pull words of previously-kept rows
                u64 myor = 0;
                for (int t = (wave - 1) * 64 + lane; t < K; t += 13 * 64)
                    myor |= mask[(u64)nb * VP + klidx[t]];
                #pragma unroll
                for (int off = 1; off < 64; off <<= 1)
                    myor |= __shfl_xor(myor, off, 64);
                if (lane == 0 && myor)
                    atomicOr((unsigned long long*)&pullw[nb & 1], myor);
            }
        } else if (wave == 14) {
            if (nb < W) {             // rows of block b -> their word nb (coalesced)
                int r_ = rb0 + lane;
                nextw[lane] = (r_ < V) ? mask[(u64)nb * VP + r_] : 0ull;
            }
        } else {                      // wave 15: diag of block nb (coalesced)
            if (nb < W) {
                int r_ = (nb << 6) + lane;
                diagb[nb & 1][lane] = (r_ < V) ? mask[(u64)nb * VP + r_] : 0ull;
            }
        }
        __syncthreads();
        // ---- phase 2: new-kept contribution + bookkeeping ----
        if (wave == 0) {
            if (nb < W) {
                u64 t = ((keptb >> lane) & 1ull) ? nextw[lane] : 0ull;
                #pragma unroll
                for (int off = 1; off < 64; off <<= 1)
                    t |= __shfl_xor(t, off, 64);
                if (lane == 0 && t)
                    atomicOr((unsigned long long*)&pullw[nb & 1], t);
            }
            if ((keptb >> lane) & 1ull) {
                int pos = (int)__popcll(keptb & ((1ull << lane) - 1ull));
                klidx[K + pos] = rb0 + lane;
            }
            if (lane == 0) Ksh = K + (int)__popcll(keptb);
        } else if (tid == 64) {
            pullw[b & 1] = 0;         // consumed; clean slot for block b+2
        }
        __syncthreads();
    }

    // ---- scatter kept rows into (pre-zeroed) out ----
    for (int k = tid; k < V; k += NT) {
        bool keep = !((rem[k >> 6] >> (k & 63)) & 1ull);
        if (keep) {
            int rk = vrank[k];
            float4 b = cbox[k];
            out[rk * 5 + 0] = b.x;
            out[rk * 5 + 1] = b.y;
            out[rk * 5 + 2] = b.z;
            out[rk * 5 + 3] = b.w;
            out[rk * 5 + 4] = cscore[k];
            out[NPROP * 5 + rk] = 1.0f;
        }
    }
}

extern "C" void kernel_launch(void* const* d_in, const int* in_sizes, int n_in,
                              void* d_out, int out_size, void* d_ws, size_t ws_size,
                              hipStream_t stream) {
    const float* boxes  = (const float*)d_in[0];
    const float* scores = (const float*)d_in[1];
    const float* img    = (const float*)d_in[2];
    char* ws = (char*)d_ws;
    unsigned* prefP  = (unsigned*)(ws + 0);      // 32 KiB
    int*    tmp_idx  = (int*)(ws + 32768);       // 32 KiB
    float*  cscore   = (float*)(ws + 65536);     // 32 KiB
    float4* cbox     = (float4*)(ws + 98304);    // 128 KiB
    int*    vrank    = (int*)(ws + 229376);      // 32 KiB
    int*    meta     = (int*)(ws + 262144);      // 1 KiB
    u64*    mask     = (u64*)(ws + 263168);      // W*VP*8 B (~200 KiB realistic)
    float* out = (float*)d_out;

    k_sort1<<<1, NT, 0, stream>>>(boxes, scores, img, prefP, tmp_idx, meta);
    k_rank<<<32, 256, 0, stream>>>(scores, boxes, tmp_idx, prefP, meta,
                                   cbox, cscore, vrank);
    k_mask<<<256, 256, 0, stream>>>(cbox, meta, mask, out);
    k_resolve<<<1, NT, 0, stream>>>(mask, meta, cbox, cscore, vrank, out);
}